// Round 2
// baseline (671.397 us; speedup 1.0000x reference)
//
#include <hip/hip_runtime.h>

// PointNet 2-stage fused pipeline, MI355X gfx950.
// Counting-sort points by voxel; f16 MFMA (16x16x32) GEMMs with
// global_load_lds(16B) + XOR-swizzled LDS; segment-max fused into GEMM
// epilogues (run-reduced over sorted rows + f32-as-int atomicMax).
// Stage-2 chunked (8x65536) to keep workspace ~119 MB; stage-1 recomputed
// per chunk. Final 256x256 layer in f32 VALU for precision.

#define NPTS 524288
#define NVOX 32768
#define CHUNK 65536
#define NCHUNK 8

typedef _Float16 f16;
typedef _Float16 f16x8 __attribute__((ext_vector_type(8)));
typedef float f32x4 __attribute__((ext_vector_type(4)));

#define GLDS16(g, l)                                                          \
  __builtin_amdgcn_global_load_lds(                                           \
      (const __attribute__((address_space(1))) unsigned int*)(const void*)(g),\
      (__attribute__((address_space(3))) unsigned int*)(void*)(l), 16, 0, 0)

// ---------- idx normalization: auto-detect int32 vs int64 storage ----------
__global__ void k_fixidx(const int* __restrict__ raw, int* __restrict__ out) {
  bool is64 = true;
#pragma unroll
  for (int k = 0; k < 32; ++k)
    if (raw[2 * k + 1] != 0) is64 = false;   // int64 high words all 0 (vals < 32768)
  int stride = gridDim.x * blockDim.x;
  for (int i = blockIdx.x * blockDim.x + threadIdx.x; i < NPTS; i += stride)
    out[i] = is64 ? raw[2 * i] : raw[i];
}

// ---------- counting sort ----------
__global__ void k_hist(const int* __restrict__ idx, int* __restrict__ counts) {
  int stride = gridDim.x * blockDim.x;
  for (int i = blockIdx.x * blockDim.x + threadIdx.x; i < NPTS; i += stride)
    atomicAdd(&counts[idx[i]], 1);
}

__global__ void k_scan(const int* __restrict__ counts, int* __restrict__ offsets) {
  __shared__ int part[1024];
  __shared__ int sums[32];
  int t = threadIdx.x;
  int loc[32];
  int s = 0;
#pragma unroll
  for (int j = 0; j < 32; ++j) { loc[j] = counts[t * 32 + j]; s += loc[j]; }
  part[t] = s;
  __syncthreads();
  if (t < 32) {
    int run = 0;
    for (int j = 0; j < 32; ++j) { int tmp = part[t * 32 + j]; part[t * 32 + j] = run; run += tmp; }
    sums[t] = run;
  }
  __syncthreads();
  if (t == 0) {
    int run = 0;
    for (int i = 0; i < 32; ++i) { int tmp = sums[i]; sums[i] = run; run += tmp; }
  }
  __syncthreads();
  int b = part[t] + sums[t >> 5];
#pragma unroll
  for (int j = 0; j < 32; ++j) { offsets[t * 32 + j] = b; b += loc[j]; }
  if (t == 1023) offsets[NVOX] = b;
}

__global__ void k_scat(const int* __restrict__ idx, const int* __restrict__ offsets,
                       int* __restrict__ cursor, int* __restrict__ sp, int* __restrict__ sv) {
  int stride = gridDim.x * blockDim.x;
  for (int i = blockIdx.x * blockDim.x + threadIdx.x; i < NPTS; i += stride) {
    int v = idx[i];
    int pos = offsets[v] + atomicAdd(&cursor[v], 1);
    sp[pos] = i;
    sv[pos] = v;
  }
}

// ---------- weight transpose+cast: Wt[n][k] = (f16)W[k][n] ----------
__global__ void k_wcast(const float* __restrict__ W, f16* __restrict__ Wt, int K, int N) {
  int g = blockIdx.x * blockDim.x + threadIdx.x;
  if (g >= K * N) return;
  int k = g / N, n = g % N;
  Wt[n * K + k] = (f16)W[g];
}

__global__ void k_castf(const float* __restrict__ in, f16* __restrict__ out, int n) {
  int stride = gridDim.x * blockDim.x;
  for (int i = blockIdx.x * blockDim.x + threadIdx.x; i < n; i += stride)
    out[i] = (f16)in[i];
}

// ---------- f16 MFMA GEMM: C = relu(A' @ B + bias), 128x128 tile / block ----
// MODEA 0: A'[r] = A[tm*128+r]           ([rows][K] f16 contiguous)
// MODEA 1: A'[r] = concat(A2[sv[g r]](128), A[tm*128+r](128)), K=256
// MODEA 2: A'[r] = f16(relu(x[sp[g r]] @ W1 + b1))  (mlp1 on the fly, K=64)
// SCATTER: run-reduce sorted-voxel rows, atomicMax into Of32[v][N]
// row0: global sorted-row offset of this launch (chunking)
template <int K, int N, int MODEA, bool SCATTER>
__global__ __launch_bounds__(256, 3) void k_gemm(
    const f16* __restrict__ A, const f16* __restrict__ A2,
    const int* __restrict__ sv, const int* __restrict__ sp,
    const float* __restrict__ x, const float* __restrict__ W1, const float* __restrict__ b1,
    const f16* __restrict__ Bt,   // [N][K] pre-transposed
    const float* __restrict__ bias,
    f16* __restrict__ Of16, float* __restrict__ Of32, int row0) {
  constexpr int NT = N / 128;
  __shared__ __align__(16) char smem[32768];
  __shared__ float xs[MODEA == 2 ? 768 : 1];
  __shared__ int svp[MODEA == 2 ? 128 : 1];
  __shared__ int svx[(MODEA == 1 || SCATTER) ? 128 : 1];
  f16* As = (f16*)smem;           // [128][64] per K-tile, 16B chunks XOR-swizzled by row&7
  f16* Bs = As + 128 * 64;

  int nwg = gridDim.x;            // all grids are multiples of 8
  int bid = blockIdx.x;
  int q = nwg >> 3;
  int swz = (bid & 7) * q + (bid >> 3);   // bijective XCD swizzle
  int tm = swz / NT, tn = swz % NT;
  int t = threadIdx.x;

  if (MODEA == 2) { if (t < 128) svp[t] = sp[row0 + tm * 128 + t]; }
  if (MODEA == 1 || SCATTER) { if (t < 128) svx[t] = sv[row0 + tm * 128 + t]; }
  if (MODEA == 1 || MODEA == 2) __syncthreads();

  int l = t & 63, w = t >> 6;
  int wm = w >> 1, wn = w & 1;
  int lrow = l & 15, lk = l >> 4;
  f32x4 acc[4][4] = {};

  constexpr int KT = K / 64;
#pragma unroll
  for (int kt = 0; kt < KT; ++kt) {
    int k0 = kt * 64;
    // ---- stage B first (issue async loads early)
#pragma unroll
    for (int i = 0; i < 4; ++i) {
      int n = i * 32 + (t >> 3);
      int clog = (t & 7) ^ (n & 7);
      GLDS16(Bt + (size_t)(tn * 128 + n) * K + k0 + clog * 8, Bs + i * 2048 + t * 8);
    }
    if constexpr (MODEA == 2) {
      // gather x rows into LDS
      for (int g = t; g < 768; g += 256) xs[g] = x[(size_t)svp[g / 6] * 6 + (g % 6)];
      __syncthreads();
      // compute mlp1 tile directly into swizzled As
      int j = t & 63;
      float wv[6];
#pragma unroll
      for (int i = 0; i < 6; ++i) wv[i] = W1[i * 64 + j];
      float bb = b1[j];
      int rb = (t >> 6) * 32;
#pragma unroll
      for (int rr = 0; rr < 32; ++rr) {
        int row = rb + rr;
        float a = bb;
#pragma unroll
        for (int i = 0; i < 6; ++i) a += xs[row * 6 + i] * wv[i];
        As[row * 64 + (((j >> 3) ^ (row & 7)) << 3) + (j & 7)] = (f16)fmaxf(a, 0.f);
      }
    } else {
#pragma unroll
      for (int i = 0; i < 4; ++i) {
        int row = i * 32 + (t >> 3);
        int clog = (t & 7) ^ (row & 7);
        const f16* src;
        if constexpr (MODEA == 0) {
          src = A + (size_t)(tm * 128 + row) * K + k0 + clog * 8;
        } else {  // MODEA == 1: gather-concat
          if (k0 < 128) src = A2 + (size_t)svx[row] * 128 + k0 + clog * 8;
          else          src = A + (size_t)(tm * 128 + row) * 128 + (k0 - 128) + clog * 8;
        }
        GLDS16(src, As + i * 2048 + t * 8);
      }
    }
    __syncthreads();   // compiler drains vmcnt+lgkmcnt before barrier
#pragma unroll
    for (int ks = 0; ks < 2; ++ks) {
      f16x8 af[4], bf[4];
#pragma unroll
      for (int m = 0; m < 4; ++m) {
        int row = wm * 64 + m * 16 + lrow;
        int cp = (ks * 4 + lk) ^ (row & 7);
        af[m] = *(const f16x8*)(As + row * 64 + cp * 8);
      }
#pragma unroll
      for (int n = 0; n < 4; ++n) {
        int col = wn * 64 + n * 16 + lrow;
        int cp = (ks * 4 + lk) ^ (col & 7);
        bf[n] = *(const f16x8*)(Bs + col * 64 + cp * 8);
      }
#pragma unroll
      for (int m = 0; m < 4; ++m)
#pragma unroll
        for (int n = 0; n < 4; ++n)
          acc[m][n] = __builtin_amdgcn_mfma_f32_16x16x32_f16(af[m], bf[n], acc[m][n], 0, 0, 0);
    }
    __syncthreads();
  }

  if constexpr (!SCATTER) {
#pragma unroll
    for (int m = 0; m < 4; ++m)
#pragma unroll
      for (int n = 0; n < 4; ++n)
#pragma unroll
        for (int j = 0; j < 4; ++j) {
          int row = wm * 64 + m * 16 + lk * 4 + j;   // C/D: row=(l>>4)*4+j
          int col = wn * 64 + n * 16 + lrow;         //      col=l&15
          int gc = tn * 128 + col;
          Of16[(size_t)(tm * 128 + row) * N + gc] = (f16)fmaxf(acc[m][n][j] + bias[gc], 0.f);
        }
  } else {
    f16* tile = (f16*)smem;   // reuse As/Bs as [128][128] f16 (32KB)
#pragma unroll
    for (int m = 0; m < 4; ++m)
#pragma unroll
      for (int n = 0; n < 4; ++n)
#pragma unroll
        for (int j = 0; j < 4; ++j) {
          int row = wm * 64 + m * 16 + lk * 4 + j;
          int col = wn * 64 + n * 16 + lrow;
          tile[row * 128 + col] = (f16)fmaxf(acc[m][n][j] + bias[tn * 128 + col], 0.f);
        }
    __syncthreads();
    // run-reduced scatter-max: rows sorted by voxel
    int c = t & 127, h = t >> 7;
    int r0 = h * 64;
    int gc = tn * 128 + c;
    float run = 0.f;
    int curv = svx[r0];
    for (int r = r0; r < r0 + 64; ++r) {
      int v = svx[r];
      if (v != curv) {
        atomicMax((int*)&Of32[(size_t)curv * N + gc], __float_as_int(run));
        curv = v; run = 0.f;
      }
      run = fmaxf(run, (float)tile[r * 128 + c]);
    }
    atomicMax((int*)&Of32[(size_t)curv * N + gc], __float_as_int(run));
  }
}

// ---------- final layer in f32 (precision): out = relu(A @ W + b) ----------
__global__ __launch_bounds__(256, 4) void k_gemm32(
    const float* __restrict__ A, const float* __restrict__ W,
    const float* __restrict__ bias, float* __restrict__ out) {
  __shared__ float As[64][33];
  __shared__ float Bs[32][64];
  int bid = blockIdx.x;
  int m0 = (bid >> 2) * 64, n0 = (bid & 3) * 64;
  int t = threadIdx.x;
  int tx = t & 15, ty = t >> 4;
  float acc[4][4] = {};
  for (int k0 = 0; k0 < 256; k0 += 32) {
#pragma unroll
    for (int it = 0; it < 2; ++it) {
      int r = (t >> 3) + it * 32;
      int c4 = (t & 7) * 4;
      float4 v = *(const float4*)(A + (size_t)(m0 + r) * 256 + k0 + c4);
      As[r][c4] = v.x; As[r][c4 + 1] = v.y; As[r][c4 + 2] = v.z; As[r][c4 + 3] = v.w;
    }
#pragma unroll
    for (int it = 0; it < 2; ++it) {
      int kk = (t >> 4) + it * 16;
      int c4 = (t & 15) * 4;
      *(float4*)&Bs[kk][c4] = *(const float4*)(W + (size_t)(k0 + kk) * 256 + n0 + c4);
    }
    __syncthreads();
#pragma unroll
    for (int k = 0; k < 32; ++k) {
      float4 bv = *(const float4*)&Bs[k][tx * 4];
      float av[4];
#pragma unroll
      for (int i = 0; i < 4; ++i) av[i] = As[ty * 4 + i][k];
#pragma unroll
      for (int i = 0; i < 4; ++i) {
        acc[i][0] += av[i] * bv.x; acc[i][1] += av[i] * bv.y;
        acc[i][2] += av[i] * bv.z; acc[i][3] += av[i] * bv.w;
      }
    }
    __syncthreads();
  }
#pragma unroll
  for (int i = 0; i < 4; ++i) {
    float4 o;
    o.x = fmaxf(acc[i][0] + bias[n0 + tx * 4 + 0], 0.f);
    o.y = fmaxf(acc[i][1] + bias[n0 + tx * 4 + 1], 0.f);
    o.z = fmaxf(acc[i][2] + bias[n0 + tx * 4 + 2], 0.f);
    o.w = fmaxf(acc[i][3] + bias[n0 + tx * 4 + 3], 0.f);
    *(float4*)&out[(size_t)(m0 + ty * 4 + i) * 256 + n0 + tx * 4] = o;
  }
}

extern "C" void kernel_launch(void* const* d_in, const int* in_sizes, int n_in,
                              void* d_out, int out_size, void* d_ws, size_t ws_size,
                              hipStream_t stream) {
  const float* x   = (const float*)d_in[0];
  const int*  idxr = (const int*)d_in[1];
  const float* W1  = (const float*)d_in[3];
  const float* b1  = (const float*)d_in[4];
  const float* W2  = (const float*)d_in[5];
  const float* b2  = (const float*)d_in[6];
  const float* Wv1 = (const float*)d_in[7];
  const float* bv1 = (const float*)d_in[8];
  const float* W3  = (const float*)d_in[9];
  const float* b3  = (const float*)d_in[10];
  const float* W4  = (const float*)d_in[11];
  const float* b4  = (const float*)d_in[12];
  const float* Wv2 = (const float*)d_in[13];
  const float* bv2 = (const float*)d_in[14];
  float* out = (float*)d_out;

  char* ws = (char*)d_ws;
  size_t off = 0;
  auto alloc = [&](size_t bytes) {
    void* p = ws + off;
    off = (off + bytes + 255) & ~(size_t)255;
    return p;
  };
  int* idx     = (int*)alloc((size_t)NPTS * 4);
  int* counts  = (int*)alloc((size_t)NVOX * 4);
  int* cursor  = (int*)alloc((size_t)NVOX * 4);
  int* offs    = (int*)alloc((size_t)(NVOX + 1) * 4);
  int* sp      = (int*)alloc((size_t)NPTS * 4);
  int* sv      = (int*)alloc((size_t)NPTS * 4);
  f16* W2t     = (f16*)alloc(64 * 128 * 2);
  f16* Wv1t    = (f16*)alloc(128 * 128 * 2);
  f16* W3t     = (f16*)alloc(256 * 256 * 2);
  f16* W4t     = (f16*)alloc(256 * 256 * 2);
  float* vox1f = (float*)alloc((size_t)NVOX * 128 * 4);
  f16* vox1h   = (f16*)alloc((size_t)NVOX * 128 * 2);
  f16* occ1    = (f16*)alloc((size_t)NVOX * 128 * 2);
  float* vox2f = (float*)alloc((size_t)NVOX * 256 * 4);
  f16* pf2c    = (f16*)alloc((size_t)CHUNK * 128 * 2);
  f16* pf4c    = (f16*)alloc((size_t)CHUNK * 256 * 2);
  // total ~119 MB

  hipMemsetAsync(counts, 0, (size_t)NVOX * 4, stream);
  hipMemsetAsync(cursor, 0, (size_t)NVOX * 4, stream);
  hipMemsetAsync(vox1f, 0, (size_t)NVOX * 128 * 4, stream);
  hipMemsetAsync(vox2f, 0, (size_t)NVOX * 256 * 4, stream);

  k_fixidx<<<2048, 256, 0, stream>>>(idxr, idx);
  k_wcast<<<(64 * 128 + 255) / 256, 256, 0, stream>>>(W2, W2t, 64, 128);
  k_wcast<<<(128 * 128 + 255) / 256, 256, 0, stream>>>(Wv1, Wv1t, 128, 128);
  k_wcast<<<(256 * 256 + 255) / 256, 256, 0, stream>>>(W3, W3t, 256, 256);
  k_wcast<<<(256 * 256 + 255) / 256, 256, 0, stream>>>(W4, W4t, 256, 256);
  k_hist<<<2048, 256, 0, stream>>>(idx, counts);
  k_scan<<<1, 1024, 0, stream>>>(counts, offs);
  k_scat<<<2048, 256, 0, stream>>>(idx, offs, cursor, sp, sv);

  // P1: fused mlp1+mm2 + segment-max -> vox1f  (all points)
  k_gemm<64, 128, 2, true><<<NPTS / 128, 256, 0, stream>>>(
      nullptr, nullptr, sv, sp, x, W1, b1, W2t, b2, nullptr, vox1f, 0);
  k_castf<<<2048, 256, 0, stream>>>(vox1f, vox1h, NVOX * 128);
  // mmv1: occ1 = relu(vox1 @ Wv1 + bv1)
  k_gemm<128, 128, 0, false><<<NVOX / 128, 256, 0, stream>>>(
      vox1h, nullptr, nullptr, nullptr, nullptr, nullptr, nullptr,
      Wv1t, bv1, occ1, nullptr, 0);

  // stage 2, chunked
  for (int c = 0; c < NCHUNK; ++c) {
    int row0 = c * CHUNK;
    // recompute pf2 for this chunk
    k_gemm<64, 128, 2, false><<<CHUNK / 128, 256, 0, stream>>>(
        nullptr, nullptr, nullptr, sp, x, W1, b1, W2t, b2, pf2c, nullptr, row0);
    // mm3: pf4c = relu(concat(occ1[sv], pf2c) @ W3 + b3)
    k_gemm<256, 256, 1, false><<<(CHUNK / 128) * 2, 256, 0, stream>>>(
        pf2c, occ1, sv, nullptr, nullptr, nullptr, nullptr,
        W3t, b3, pf4c, nullptr, row0);
    // mm4 + scatter-max into vox2f
    k_gemm<256, 256, 0, true><<<(CHUNK / 128) * 2, 256, 0, stream>>>(
        pf4c, nullptr, sv, nullptr, nullptr, nullptr, nullptr,
        W4t, b4, nullptr, vox2f, row0);
  }

  // final layer f32: out = relu(vox2f @ Wv2 + bv2)
  k_gemm32<<<(NVOX / 64) * 4, 256, 0, stream>>>(vox2f, Wv2, bv2, out);
}